// Round 8
// baseline (206.698 us; speedup 1.0000x reference)
//
#include <hip/hip_runtime.h>

#define NEG (-1e9f)
constexpr int NCLS   = 21;
constexpr int NBOX   = 8732;
constexpr int MAXOUT = 5;
constexpr int CAP    = NBOX;          // worst-case candidates per batch
constexpr float IOU_THR  = 0.5f;
constexpr float CONF_THR = 0.5f;

constexpr int TPB             = 256;
constexpr int BOXES_PER_BLOCK = TPB * 4;                                   // 1024
constexpr int BPB             = (NBOX + BOXES_PER_BLOCK - 1) / BOXES_PER_BLOCK; // 9

using u64 = unsigned long long;
typedef float f4_t __attribute__((ext_vector_type(4)));

// ---------------------------------------------------------------------------
// Fused kernel v8: decode + compaction + last-block-done NMS (zero-fence
// protocol, proven absmax 0.0 R3-R7), decode rebuilt as TWO-PASS STREAMING
// RUNNING-STATE reduction.
// R3-R7 unified post-mortem: every structure (reg-staged, asm-batched,
// LDS-staged, 2-box/f2) hit the same ~70-90us because the per-box max->sum
// reduction compiled to a serial load->use chain (loads sunk to first use;
// R7's VGPR=24 + FETCH 57->76MB proves the compiler even RELOADED the class
// logits for the sum pass). Occupancy/MLP never touched that chain.
// v8 shape (cf. m146 RMSNorm 2-pass streaming, 4.89 TB/s): per thread,
// 4 boxes (float4-aligned group), running state only:
//   pass1: stream 25 float4, update (mx[j], am[j]) running max/argmax,
//          stash loc[j][0..3];
//   asm volatile("" ::: "memory")  -- zero-cost compiler barrier: forbids
//          CSE of pass2 loads with pass1 (no 84-float live range, no spill);
//          pass2 re-loads hit L1 (wave working set 25.6KB).
//   pass2: stream again, sm[j] = / += expf(x - mx[j]) in reference order
//          (init at l==4 is 0+exp == exp, exact).
// Every load's consumer is a 4-cyc register op -> compiler pipelines loads
// 4-8 deep; per-box critical path ~21x4 VALU cycles instead of ~25xL1-lat.
// All state is constant-indexed 4-arrays (SROA-safe, rule #20 is about
// runtime indexing). Bit-exact: same chain orders, same expf, same decode.
// Protocol: relaxed agent-scope atomics; __syncthreads drains vmcnt before
// done[b] RMW (proven). NMS: M<=64 register-resident fast path + M>64
// global fallback (verbatim R3).
// Candidate record: u64 w0=(y1,x1) w1=(y2,x2) w2=(score,oid) w3=(cls,0).
// ---------------------------------------------------------------------------

__device__ __forceinline__ u64 pk2(float a, float b) {
    union { float f[2]; u64 u; } x; x.f[0] = a; x.f[1] = b; return x.u;
}
__device__ __forceinline__ float lo2(u64 u) { union { u64 v; float f[2]; } x; x.v = u; return x.f[0]; }
__device__ __forceinline__ float hi2(u64 u) { union { u64 v; float f[2]; } x; x.v = u; return x.f[1]; }

__device__ __forceinline__ void ast(u64* p, u64 v) {
    __hip_atomic_store(p, v, __ATOMIC_RELAXED, __HIP_MEMORY_SCOPE_AGENT);
}
__device__ __forceinline__ u64 ald(const u64* p) {
    return __hip_atomic_load(p, __ATOMIC_RELAXED, __HIP_MEMORY_SCOPE_AGENT);
}

__global__ __launch_bounds__(TPB) void fused_kernel(
        const float* __restrict__ logits,
        const float4* __restrict__ dbox4,
        u64* __restrict__ cand,
        int* __restrict__ cnt,
        int* __restrict__ done,
        float* __restrict__ out) {
    const int b   = blockIdx.x / BPB;
    const int blk = blockIdx.x % BPB;
    const int t   = threadIdx.x;
    const int n0  = blk * BOXES_PER_BLOCK + t * 4;   // box idx within batch

    __shared__ int s_last;    // ONLY LDS in the kernel (4 bytes)

    // ---- decode phase: two-pass streaming, running state ------------------
    if (n0 < NBOX) {
        // group base: (b*NBOX+n0)*100 bytes, n0%4==0 -> 16B-aligned
        const f4_t* f4  = (const f4_t*)(logits + ((long long)b * NBOX + n0) * 25);
        const f4_t* dbp = (const f4_t*)dbox4;

        float mx[4];            // running max of class logits per box
        int   am[4];            // running argmax (class index) per box
        float sm[4];            // softmax denominator per box
        float loc[4][4];        // (dy,dx,dh,dw) per box

        // -- pass 1: running max/argmax + loc stash (order: g ascending == l
        //    ascending per box == reference chain order) --
#pragma unroll
        for (int k = 0; k < 25; k++) {
            f4_t r = f4[k];
#pragma unroll
            for (int c = 0; c < 4; c++) {
                const int g = 4 * k + c;      // compile-time constants
                const int j = g / 25;
                const int l = g - 25 * j;
                float x = r[c];
                if (l < 4) {
                    loc[j][l] = x;
                } else if (l == 4) {
                    mx[j] = x; am[j] = 0;
                } else {
                    if (x > mx[j]) { mx[j] = x; am[j] = l - 4; }
                }
            }
        }

        // compiler barrier: pass-2 loads may NOT be CSE'd with pass-1 values
        // (no instruction emitted; registers unconstrained; L1 re-hits)
        asm volatile("" ::: "memory");

        // -- pass 2: softmax denominator, reference accumulation order --
#pragma unroll
        for (int k = 0; k < 25; k++) {
            f4_t r = f4[k];
#pragma unroll
            for (int c = 0; c < 4; c++) {
                const int g = 4 * k + c;
                const int j = g / 25;
                const int l = g - 25 * j;
                float x = r[c];
                if (l == 4) {
                    sm[j] = expf(x - mx[j]);              // sum=0; sum+=exp -> exact
                } else if (l > 4) {
                    sm[j] += expf(x - mx[j]);
                }
            }
        }

        // -- epilogue: score, filter, decode, candidate append --
#pragma unroll
        for (int j = 0; j < 4; j++) {
            float score = 1.0f / sm[j];
            if (am[j] != 0 && score > CONF_THR) {
                f4_t db = dbp[n0 + j];
                float cy = (db[2] + db[0]) * 0.5f;
                float cx = (db[3] + db[1]) * 0.5f;
                float h  = db[2] - db[0];
                float w  = db[3] - db[1];
                float ncy = loc[j][0] * h + cy;
                float ncx = loc[j][1] * w + cx;
                float nh  = expf(loc[j][2]) * h;
                float nw  = expf(loc[j][3]) * w;
                float y1 = fminf(fmaxf(ncy - nh * 0.5f, 0.f), 1.f);
                float x1 = fminf(fmaxf(ncx - nw * 0.5f, 0.f), 1.f);
                float y2 = fminf(fmaxf(ncy + nh * 0.5f, 0.f), 1.f);
                float x2 = fminf(fmaxf(ncx + nw * 0.5f, 0.f), 1.f);

                int p = atomicAdd(&cnt[b], 1);   // device-scope RMW
                if (p < CAP) {
                    u64* c = cand + ((long long)b * CAP + p) * 4;
                    ast(c + 0, pk2(y1, x1));
                    ast(c + 1, pk2(y2, x2));
                    ast(c + 2, pk2(score, (float)(n0 + j)));
                    ast(c + 3, pk2((float)am[j], 0.f));
                }
            }
        }
    }

    // ---- completion protocol: zero fences (proven R3) ---------------------
    // __syncthreads drains each wave's vmcnt (sc-flagged stores then globally
    // visible) before the relaxed device-scope RMW on done[b].
    __syncthreads();
    if (threadIdx.x == 0)
        s_last = (__hip_atomic_fetch_add(&done[b], 1, __ATOMIC_RELAXED,
                                         __HIP_MEMORY_SCOPE_AGENT) == BPB - 1);
    __syncthreads();
    if (!s_last) return;             // not the last block for this batch
    if (threadIdx.x >= 64) return;   // NMS = exactly one wave

    // ---- NMS phase (verbatim R3, proven) ----------------------------------
    const int lane = threadIdx.x;
    const int M = min((int)__hip_atomic_load(&cnt[b], __ATOMIC_RELAXED,
                                             __HIP_MEMORY_SCOPE_AGENT), CAP);
    const u64* cb = cand + (long long)b * CAP * 4;
    float* o = out + (long long)b * MAXOUT * 6;

    int k = 0;
    if (M <= 64) {
        // register-resident fast path: one candidate per lane, zero memory
        // traffic inside the selection loop.
        float sc = -INFINITY, oid = 3.0e38f;
        float y1 = 0.f, x1 = 0.f, y2 = 0.f, x2 = 0.f, cls = 0.f;
        if (lane < M) {
            const u64* c = cb + (long long)lane * 4;
            u64 w0 = ald(c + 0), w1 = ald(c + 1), w2 = ald(c + 2), w3 = ald(c + 3);
            y1 = lo2(w0); x1 = hi2(w0);
            y2 = lo2(w1); x2 = hi2(w1);
            sc = lo2(w2); oid = hi2(w2);
            cls = lo2(w3);
        }
        for (; k < MAXOUT; k++) {
            float bv = sc, boid = oid;
            int bi = (lane < M) ? lane : -1;
            for (int mm = 32; mm >= 1; mm >>= 1) {
                float v2 = __shfl_xor(bv,   mm, 64);
                float o2 = __shfl_xor(boid, mm, 64);
                int   i2 = __shfl_xor(bi,   mm, 64);
                if (v2 > bv || (v2 == bv && o2 < boid)) { bv = v2; boid = o2; bi = i2; }
            }
            if (bi < 0 || !(bv > CONF_THR)) break;   // this & later slots -> zeros

            float sy1 = __shfl(y1, bi, 64), sx1 = __shfl(x1, bi, 64);
            float sy2 = __shfl(y2, bi, 64), sx2 = __shfl(x2, bi, 64);
            float scl = __shfl(cls, bi, 64);
            if (lane == 0) {
                o[k * 6 + 0] = sy1; o[k * 6 + 1] = sx1;
                o[k * 6 + 2] = sy2; o[k * 6 + 3] = sx2;
                o[k * 6 + 4] = scl; o[k * 6 + 5] = bv;
            }
            // in-register suppression (selected lane suppresses itself, IoU=1)
            float a1 = (sy2 - sy1) * (sx2 - sx1);
            float tly = fmaxf(sy1, y1);
            float tlx = fmaxf(sx1, x1);
            float bry = fminf(sy2, y2);
            float brx = fminf(sx2, x2);
            float wh0 = fmaxf(bry - tly, 0.f);
            float wh1 = fmaxf(brx - tlx, 0.f);
            float inter = wh0 * wh1;
            float a2 = (y2 - y1) * (x2 - x1);
            float iou = inter / (a1 + a2 - inter + 1e-12f);
            if (lane < M && iou > IOU_THR) sc = NEG;
        }
    } else {
        // general path (never taken for this input; worst-case correctness)
        for (; k < MAXOUT; k++) {
            float bv = -INFINITY, boid = 3.0e38f;
            int bi = -1;
            for (int i = lane; i < M; i += 64) {
                u64 w2 = ald(cb + (long long)i * 4 + 2);
                float v = lo2(w2), od = hi2(w2);
                if (v > bv || (v == bv && od < boid)) { bv = v; boid = od; bi = i; }
            }
            for (int mm = 32; mm >= 1; mm >>= 1) {
                float v2 = __shfl_xor(bv,   mm, 64);
                float o2 = __shfl_xor(boid, mm, 64);
                int   i2 = __shfl_xor(bi,   mm, 64);
                if (v2 > bv || (v2 == bv && o2 < boid)) { bv = v2; boid = o2; bi = i2; }
            }
            if (bi < 0 || !(bv > CONF_THR)) break;

            u64 sw0 = ald(cb + (long long)bi * 4 + 0);
            u64 sw1 = ald(cb + (long long)bi * 4 + 1);
            float sy1 = lo2(sw0), sx1 = hi2(sw0), sy2 = lo2(sw1), sx2 = hi2(sw1);
            if (lane == 0) {
                u64 sw3 = ald(cb + (long long)bi * 4 + 3);
                o[k * 6 + 0] = sy1; o[k * 6 + 1] = sx1;
                o[k * 6 + 2] = sy2; o[k * 6 + 3] = sx2;
                o[k * 6 + 4] = lo2(sw3); o[k * 6 + 5] = bv;
            }
            float a1 = (sy2 - sy1) * (sx2 - sx1);
            for (int i = lane; i < M; i += 64) {
                u64 w0 = ald(cb + (long long)i * 4 + 0);
                u64 w1 = ald(cb + (long long)i * 4 + 1);
                float cy1 = lo2(w0), cx1 = hi2(w0), cy2 = lo2(w1), cx2 = hi2(w1);
                float tly = fmaxf(sy1, cy1);
                float tlx = fmaxf(sx1, cx1);
                float bry = fminf(sy2, cy2);
                float brx = fminf(sx2, cx2);
                float wh0 = fmaxf(bry - tly, 0.f);
                float wh1 = fmaxf(brx - tlx, 0.f);
                float inter = wh0 * wh1;
                float a2 = (cy2 - cy1) * (cx2 - cx1);
                float iou = inter / (a1 + a2 - inter + 1e-12f);
                if (iou > IOU_THR) {
                    u64 w2 = ald(cb + (long long)i * 4 + 2);   // owner lane only
                    ast((u64*)(cb + (long long)i * 4 + 2), pk2(NEG, hi2(w2)));
                }
            }
        }
    }
    for (int j = k * 6 + lane; j < MAXOUT * 6; j += 64) o[j] = 0.f;
}

extern "C" void kernel_launch(void* const* d_in, const int* in_sizes, int n_in,
                              void* d_out, int out_size, void* d_ws, size_t ws_size,
                              hipStream_t stream) {
    const float* logits = (const float*)d_in[0];
    const float4* dbox4 = (const float4*)d_in[1];
    float* out          = (float*)d_out;

    const int N = in_sizes[1] / 4;            // 8732
    const int B = in_sizes[0] / (N * 25);     // 128

    // ws layout: [cnt: B ints][done: B ints][pad to 16B][cand: B*CAP*4 u64]
    int* cnt  = (int*)d_ws;
    int* done = cnt + B;
    u64* cand = (u64*)((char*)d_ws +
        ((2 * (size_t)B * sizeof(int) + 15) & ~(size_t)15));

    hipMemsetAsync(d_ws, 0, 2 * (size_t)B * sizeof(int), stream);
    fused_kernel<<<B * BPB, TPB, 0, stream>>>(logits, dbox4, cand, cnt, done, out);
}